// Round 3
// baseline (818.963 us; speedup 1.0000x reference)
//
#include <hip/hip_runtime.h>
#include <hip/hip_bf16.h>

// LinearPreMix: qkv = x @ W_qkv^T, split q,k,v, [B,S,E]->[B,H,S,DK]
// Pass 1: cast x,W fp32->bf16 into d_ws.
// Pass 2: persistent 256x256 8-phase GEMM, 6 tiles/block, seamless pipeline,
//         previous tile's stores interleaved 2/phase into next tile's loop.

constexpr int Bb = 4, Ss = 4096, Ee = 2048, Hh = 16, Dk = 128;
constexpr int Mm = Bb * Ss;   // 16384
constexpr int Nn = 3 * Ee;    // 6144
constexpr int Kk = Ee;        // 2048

typedef __bf16 bf16_t;
typedef __bf16 bf16x8 __attribute__((ext_vector_type(8)));
typedef float  f32x4  __attribute__((ext_vector_type(4)));

// ---------------------------------------------------------------- cast pass
__global__ __launch_bounds__(256)
void cast_f32_to_bf16(const float* __restrict__ x, const float* __restrict__ w,
                      bf16_t* __restrict__ xb, bf16_t* __restrict__ wb)
{
    const long XG = (long)Mm * Kk / 8;
    const long TG = XG + (long)Nn * Kk / 8;
    const long stride = (long)gridDim.x * blockDim.x;
    for (long g = (long)blockIdx.x * blockDim.x + threadIdx.x; g < TG; g += stride) {
        const float* s; bf16_t* d;
        if (g < XG) { s = x + g * 8;        d = xb + g * 8; }
        else        { s = w + (g - XG) * 8; d = wb + (g - XG) * 8; }
        f32x4 lo = *(const f32x4*)s;
        f32x4 hi = *(const f32x4*)(s + 4);
        bf16x8 o;
#pragma unroll
        for (int j = 0; j < 4; ++j) { o[j] = (bf16_t)lo[j]; o[j + 4] = (bf16_t)hi[j]; }
        *(bf16x8*)d = o;
    }
}

// ------------------------------------------------------- persistent GEMM
constexpr int BM = 256, BN = 256;
constexpr long BSTEP = (long)1024 * Kk;  // 4 bn-panels of 256 rows per tile step

#define GLL16(GSRC, LDST) \
  __builtin_amdgcn_global_load_lds((const __attribute__((address_space(1))) void*)(GSRC), \
                                   (__attribute__((address_space(3))) void*)(LDST), 16, 0, 0)

#define STAGE_A(BUF, KH, OFS) do { \
    bf16_t* _d = sA + ((BUF) * 2 + (KH)) * 8192 + wid * 512; \
    GLL16(srcA0 + (OFS), _d); \
    GLL16(srcA1 + (OFS), _d + 4096); \
} while (0)

#define STAGE_B(BUF, KH, P0, P1, OFS) do { \
    bf16_t* _d = sB + ((BUF) * 2 + (KH)) * 8192 + wid * 512; \
    GLL16((P0) + (OFS), _d); \
    GLL16((P1) + (OFS), _d + 4096); \
} while (0)

#define NOST ((void)0)
#define NONE ((void)0)
#define W4 asm volatile("s_waitcnt vmcnt(4)" ::: "memory")
#define W8 asm volatile("s_waitcnt vmcnt(8)" ::: "memory")

// output offset for acc element (i = mh*4+mf, nf, r); lane parts live in vbase
#define OFF(i, nf, r) (((((i) >> 2) * 64 + ((i) & 3) * 16 + (r)) * 128) + (nf) * 16)

// store pair n, n+1 (n even): n -> (i=n>>4, nf=(n>>2)&3, r=n&3)
#define ST2(n) do { \
    obp[OFF(((n) >> 4), (((n) >> 2) & 3), ((n) & 3))] = \
        sbuf[(n) >> 4][((n) >> 2) & 3][(n) & 3]; \
    obp[OFF((((n)+1) >> 4), ((((n)+1) >> 2) & 3), (((n)+1) & 3))] = \
        sbuf[((n)+1) >> 4][(((n)+1) >> 2) & 3][((n)+1) & 3]; \
} while (0)

#define PHASE(BUF, KS, MH, LOADB, STAGE_STMT, STORE_STMT, WAIT_STMT) do { \
    _Pragma("unroll") \
    for (int mf = 0; mf < 4; ++mf) { \
        int r = wm * 128 + (MH) * 64 + mf * 16 + (lane & 15); \
        int q = r * 4 + (kc ^ ((r >> 1) & 3)); \
        a[mf] = *(const bf16x8*)(sA + ((BUF) * 2 + (KS)) * 8192 + q * 8); \
    } \
    if (LOADB) { \
        _Pragma("unroll") \
        for (int nf = 0; nf < 4; ++nf) { \
            int cr = wn * 64 + nf * 16 + (lane & 15); \
            int q = cr * 4 + (kc ^ ((cr >> 1) & 3)); \
            b[nf] = *(const bf16x8*)(sB + ((BUF) * 2 + (KS)) * 8192 + q * 8); \
        } \
    } \
    STAGE_STMT; \
    __builtin_amdgcn_sched_barrier(0); \
    __builtin_amdgcn_s_barrier(); \
    asm volatile("s_waitcnt lgkmcnt(0)" ::: "memory"); \
    __builtin_amdgcn_sched_barrier(0); \
    __builtin_amdgcn_s_setprio(1); \
    _Pragma("unroll") \
    for (int mf = 0; mf < 4; ++mf) { \
        _Pragma("unroll") \
        for (int nf = 0; nf < 4; ++nf) \
            acc[(MH) * 4 + mf][nf] = __builtin_amdgcn_mfma_f32_16x16x32_bf16( \
                a[mf], b[nf], acc[(MH) * 4 + mf][nf], 0, 0, 0); \
    } \
    __builtin_amdgcn_s_setprio(0); \
    STORE_STMT; \
    WAIT_STMT; \
    __builtin_amdgcn_sched_barrier(0); \
    __builtin_amdgcn_s_barrier(); \
} while (0)

// one iteration = 2 K-tiles (BK=64 each), 8 phases
#define OCTET(KB, B0S, B1S, S0,S1,S2,S3,S4,S5,S6,S7, WMID, WEND) \
    PHASE(0,0,0,1, STAGE_A(1,1,((KB)+ 96)&2047),               S0, NONE); \
    PHASE(0,0,1,0, STAGE_B(1,1,cB0,cB1,(KB)+96),               S1, NONE); \
    PHASE(0,1,0,1, STAGE_A(0,0,((KB)+128)&2047),               S2, NONE); \
    PHASE(0,1,1,0, STAGE_B(0,0,B0S,B1S,((KB)+128)&2047),       S3, WMID); \
    PHASE(1,0,0,1, STAGE_A(0,1,((KB)+160)&2047),               S4, NONE); \
    PHASE(1,0,1,0, STAGE_B(0,1,B0S,B1S,((KB)+160)&2047),       S5, NONE); \
    PHASE(1,1,0,1, STAGE_A(1,0,((KB)+192)&2047),               S6, NONE); \
    PHASE(1,1,1,0, STAGE_B(1,0,B0S,B1S,((KB)+192)&2047),       S7, WEND);

#define BOUNDARY(T) do { \
    _Pragma("unroll") \
    for (int i = 0; i < 8; ++i) \
    _Pragma("unroll") \
    for (int nf = 0; nf < 4; ++nf) { \
        sbuf[i][nf] = acc[i][nf]; \
        acc[i][nf] = f32x4{0.f, 0.f, 0.f, 0.f}; \
    } \
    obp = out_base(bn0 + 4 * (T)) + vbase; \
    cB0 = nB0; cB1 = nB1; \
    if ((T) == 4) { nB0 -= 5 * BSTEP; nB1 -= 5 * BSTEP; } \
    else         { nB0 += BSTEP;     nB1 += BSTEP; } \
} while (0)

__global__ __launch_bounds__(512, 2)
void qkv_gemm8p(const bf16_t* __restrict__ xb, const bf16_t* __restrict__ wb,
                float* __restrict__ out)
{
    extern __shared__ __attribute__((aligned(16))) char smem_raw[];
    bf16_t* sA = (bf16_t*)smem_raw;               // [2buf][2kh][8192]  64 KiB
    bf16_t* sB = (bf16_t*)(smem_raw + 65536);     // [2buf][2kh][8192]  64 KiB

    const int tid  = threadIdx.x;
    const int lane = tid & 63;
    const int wid  = tid >> 6;
    const int wm   = wid >> 2;    // 0..1
    const int wn   = wid & 3;     // 0..3
    const int kc   = lane >> 4;

    // persistent mapping: 256 blocks; fixed bm per block, bn walks +4 per tile
    const int blk = blockIdx.x;
    const int xcd = blk & 7, cu = blk >> 3;
    const int bm  = xcd * 8 + (cu >> 2);   // 0..63
    const int bn0 = cu & 3;                // tile t: bn = bn0 + 4t
    const int m0  = bm * BM;

    // pre-swizzled staging sources (rule #21: linear LDS dest, swizzled src)
    const int r0  = tid >> 2;
    const int cl0 = (tid & 3) ^ ((r0 >> 1) & 3);
    const bf16_t* srcA0 = xb + (size_t)(m0 + r0) * Kk + cl0 * 8;
    const bf16_t* srcA1 = srcA0 + (size_t)128 * Kk;
    const bf16_t* cB0 = wb + (size_t)(bn0 * 256 + r0) * Kk + cl0 * 8;
    const bf16_t* cB1 = cB0 + (size_t)128 * Kk;
    const bf16_t* nB0 = cB0 + BSTEP;
    const bf16_t* nB1 = cB1 + BSTEP;

    const int bb    = m0 >> 12;
    const int srow  = (m0 & (Ss - 1)) + wm * 128;
    const int vbase = ((lane >> 4) * 4) * Dk + (lane & 15);

    auto out_base = [&](int bn_) -> float* {
        const int n0_   = bn_ * 256;
        const int which = n0_ >> 11;
        const int hh    = ((n0_ & (Ee - 1)) >> 7) + (wn >> 1);
        return out + (((size_t)(which * Bb + bb) * Hh + hh) * Ss + srow) * Dk
                   + (wn & 1) * 64;
    };

    float* obp = out;  // set properly at first boundary (unused for t=0)

    bf16x8 a[4], b[4];
    f32x4 acc[8][4] = {};
    f32x4 sbuf[8][4];

    // prologue: stage tile0 k-tiles 0,1 fully + k-tile 2 pending
    STAGE_A(0, 0, 0);  STAGE_B(0, 0, cB0, cB1, 0);
    STAGE_A(0, 1, 32); STAGE_B(0, 1, cB0, cB1, 32);
    STAGE_A(1, 0, 64); STAGE_B(1, 0, cB0, cB1, 64);
    W4;
    __builtin_amdgcn_s_barrier();

    // ---- tile 0: fully rolled, no stores
#pragma unroll 1
    for (int it = 0; it < 16; ++it) {
        const int kb = it * 128;
        const bf16_t* b0s = (it == 15) ? nB0 : cB0;
        const bf16_t* b1s = (it == 15) ? nB1 : cB1;
        OCTET(kb, b0s, b1s, NOST,NOST,NOST,NOST,NOST,NOST,NOST,NOST, W4, W4)
    }
    BOUNDARY(0);

    // ---- tiles 1..5: first 8 iterations unrolled with interleaved stores
#pragma unroll 1
    for (int t = 1; t < 6; ++t) {
        OCTET(  0, cB0,cB1, ST2(  0),ST2(  2),ST2(  4),ST2(  6),ST2(  8),ST2( 10),ST2( 12),ST2( 14), W8, W8)
        OCTET(128, cB0,cB1, ST2( 16),ST2( 18),ST2( 20),ST2( 22),ST2( 24),ST2( 26),ST2( 28),ST2( 30), W8, W8)
        OCTET(256, cB0,cB1, ST2( 32),ST2( 34),ST2( 36),ST2( 38),ST2( 40),ST2( 42),ST2( 44),ST2( 46), W8, W8)
        OCTET(384, cB0,cB1, ST2( 48),ST2( 50),ST2( 52),ST2( 54),ST2( 56),ST2( 58),ST2( 60),ST2( 62), W8, W8)
        OCTET(512, cB0,cB1, ST2( 64),ST2( 66),ST2( 68),ST2( 70),ST2( 72),ST2( 74),ST2( 76),ST2( 78), W8, W8)
        OCTET(640, cB0,cB1, ST2( 80),ST2( 82),ST2( 84),ST2( 86),ST2( 88),ST2( 90),ST2( 92),ST2( 94), W8, W8)
        OCTET(768, cB0,cB1, ST2( 96),ST2( 98),ST2(100),ST2(102),ST2(104),ST2(106),ST2(108),ST2(110), W8, W8)
        OCTET(896, cB0,cB1, ST2(112),ST2(114),ST2(116),ST2(118),ST2(120),ST2(122),ST2(124),ST2(126), W8, W8)
#pragma unroll 1
        for (int it = 8; it < 16; ++it) {
            const int kb = it * 128;
            const bf16_t* b0s = (it == 15) ? nB0 : cB0;
            const bf16_t* b1s = (it == 15) ? nB1 : cB1;
            OCTET(kb, b0s, b1s, NOST,NOST,NOST,NOST,NOST,NOST,NOST,NOST, W4, W4)
        }
        BOUNDARY(t);
    }

    // ---- final epilogue: tile 5 results (sbuf) -> obp
#pragma unroll
    for (int i = 0; i < 8; ++i)
#pragma unroll
        for (int nf = 0; nf < 4; ++nf)
#pragma unroll
            for (int r = 0; r < 4; ++r)
                obp[OFF(i, nf, r)] = sbuf[i][nf][r];
}

// ------------------------------------------- fallback (fp32 reg staging)
constexpr int FTM = 128, FTN = 128, FTK = 64;
constexpr int FNKT = Kk / FTK;

__global__ __launch_bounds__(256, 2)
void qkv_gemm_fb(const float* __restrict__ x, const float* __restrict__ w,
                 float* __restrict__ out)
{
    __shared__ __attribute__((aligned(16))) bf16_t lA[2][FTM * FTK];
    __shared__ __attribute__((aligned(16))) bf16_t lB[2][FTN * FTK];

    const int tid = threadIdx.x, lane = tid & 63, wid = tid >> 6;
    const int wm = wid >> 1, wn = wid & 1;
    const int n0 = blockIdx.x * FTN, m0 = blockIdx.y * FTM;
    f32x4 ra[8], rb[8];

    auto load_regs = [&](int kt) {
        const int k0 = kt * FTK;
#pragma unroll
        for (int i = 0; i < 4; ++i) {
            const int c = tid + i * 256, row = c >> 3, cir = c & 7;
            const float* pa = x + (size_t)(m0 + row) * Kk + k0 + cir * 8;
            const float* pb = w + (size_t)(n0 + row) * Kk + k0 + cir * 8;
            ra[i*2+0] = *(const f32x4*)(pa); ra[i*2+1] = *(const f32x4*)(pa+4);
            rb[i*2+0] = *(const f32x4*)(pb); rb[i*2+1] = *(const f32x4*)(pb+4);
        }
    };
    auto store_lds = [&](int buf) {
#pragma unroll
        for (int i = 0; i < 4; ++i) {
            const int c = tid + i * 256, row = c >> 3, cir = c & 7;
            const int chunk = row * 8 + (cir ^ (row & 7));
            bf16x8 va, vb;
#pragma unroll
            for (int j = 0; j < 4; ++j) {
                va[j] = (bf16_t)ra[i*2+0][j]; va[j+4] = (bf16_t)ra[i*2+1][j];
                vb[j] = (bf16_t)rb[i*2+0][j]; vb[j+4] = (bf16_t)rb[i*2+1][j];
            }
            *(bf16x8*)(&lA[buf][chunk*8]) = va;
            *(bf16x8*)(&lB[buf][chunk*8]) = vb;
        }
    };
    f32x4 acc[4][4] = {};
    auto compute = [&](int buf) {
#pragma unroll
        for (int ks = 0; ks < 2; ++ks) {
            bf16x8 af[4], bfr[4];
#pragma unroll
            for (int mi = 0; mi < 4; ++mi) {
                const int row = wm*64 + mi*16 + (lane & 15);
                const int cir = ks*4 + (lane >> 4);
                af[mi] = *(const bf16x8*)(&lA[buf][(row*8 + (cir ^ (row & 7)))*8]);
            }
#pragma unroll
            for (int ni = 0; ni < 4; ++ni) {
                const int row = wn*64 + ni*16 + (lane & 15);
                const int cir = ks*4 + (lane >> 4);
                bfr[ni] = *(const bf16x8*)(&lB[buf][(row*8 + (cir ^ (row & 7)))*8]);
            }
#pragma unroll
            for (int mi = 0; mi < 4; ++mi)
#pragma unroll
                for (int ni = 0; ni < 4; ++ni)
                    acc[mi][ni] = __builtin_amdgcn_mfma_f32_16x16x32_bf16(af[mi], bfr[ni], acc[mi][ni], 0, 0, 0);
        }
    };

    load_regs(0); store_lds(0);
    int cur = 0;
#pragma unroll 1
    for (int kt = 0; kt < FNKT; ++kt) {
        __syncthreads();
        if (kt + 1 < FNKT) load_regs(kt + 1);
        compute(cur);
        if (kt + 1 < FNKT) store_lds(cur ^ 1);
        cur ^= 1;
    }
    const int b = m0 / Ss, s0g = m0 % Ss;
    const int which = n0 >> 11, h = (n0 & (Ee - 1)) >> 7;
    float* obase = out + ((size_t)((which * Bb + b) * Hh + h) * Ss + s0g) * Dk;
#pragma unroll
    for (int mi = 0; mi < 4; ++mi)
#pragma unroll
        for (int ni = 0; ni < 4; ++ni)
#pragma unroll
            for (int r = 0; r < 4; ++r) {
                const int rowL = wm*64 + mi*16 + (lane >> 4)*4 + r;
                const int colL = wn*64 + ni*16 + (lane & 15);
                obase[(size_t)rowL * Dk + colL] = acc[mi][ni][r];
            }
}

// ---------------------------------------------------------------- launcher
extern "C" void kernel_launch(void* const* d_in, const int* in_sizes, int n_in,
                              void* d_out, int out_size, void* d_ws, size_t ws_size,
                              hipStream_t stream) {
    const float* x = (const float*)d_in[0];
    const float* w = (const float*)d_in[1];
    float* out = (float*)d_out;

    const size_t xb_bytes = (size_t)Mm * Kk * 2;
    const size_t wb_bytes = (size_t)Nn * Kk * 2;

    if (ws_size >= xb_bytes + wb_bytes) {
        bf16_t* xb = (bf16_t*)d_ws;
        bf16_t* wb = (bf16_t*)((char*)d_ws + xb_bytes);
        cast_f32_to_bf16<<<2048, 256, 0, stream>>>(x, w, xb, wb);
        hipFuncSetAttribute((const void*)qkv_gemm8p,
                            hipFuncAttributeMaxDynamicSharedMemorySize, 131072);
        qkv_gemm8p<<<256, 512, 131072, stream>>>(xb, wb, out);
    } else {
        dim3 grid(Nn / FTN, Mm / FTM);
        qkv_gemm_fb<<<grid, dim3(256), 0, stream>>>(x, w, out);
    }
}

// Round 4
// 447.251 us; speedup vs baseline: 1.8311x; 1.8311x over previous
//
#include <hip/hip_runtime.h>
#include <hip/hip_bf16.h>

// LinearPreMix: qkv = x @ W_qkv^T, split to q,k,v, reshape [B,S,E]->[B,H,S,DK]
// Pass 1: cast x,W fp32->bf16 into d_ws.
// Pass 2: 256x256 8-phase counted-vmcnt bf16 MFMA GEMM (guide §5 template).
// r4: epilogue uses non-temporal stores (output bypasses L3 -> inputs stay
//     L3-resident) + line-contiguous (i,r,nf) store order. Otherwise = r2.

constexpr int Bb = 4, Ss = 4096, Ee = 2048, Hh = 16, Dk = 128;
constexpr int Mm = Bb * Ss;   // 16384
constexpr int Nn = 3 * Ee;    // 6144
constexpr int Kk = Ee;        // 2048

typedef __bf16 bf16_t;
typedef __bf16 bf16x8 __attribute__((ext_vector_type(8)));
typedef float  f32x4  __attribute__((ext_vector_type(4)));

// ---------------------------------------------------------------- cast pass
__global__ __launch_bounds__(256)
void cast_f32_to_bf16(const float* __restrict__ x, const float* __restrict__ w,
                      bf16_t* __restrict__ xb, bf16_t* __restrict__ wb)
{
    const long XG = (long)Mm * Kk / 8;            // x groups of 8
    const long TG = XG + (long)Nn * Kk / 8;       // total groups
    const long stride = (long)gridDim.x * blockDim.x;
    for (long g = (long)blockIdx.x * blockDim.x + threadIdx.x; g < TG; g += stride) {
        const float* s; bf16_t* d;
        if (g < XG) { s = x + g * 8;        d = xb + g * 8; }
        else        { s = w + (g - XG) * 8; d = wb + (g - XG) * 8; }
        f32x4 lo = *(const f32x4*)s;
        f32x4 hi = *(const f32x4*)(s + 4);
        bf16x8 o;
#pragma unroll
        for (int j = 0; j < 4; ++j) { o[j] = (bf16_t)lo[j]; o[j + 4] = (bf16_t)hi[j]; }
        *(bf16x8*)d = o;
    }
}

// ------------------------------------------------------- 8-phase 256² GEMM
constexpr int BM = 256, BN = 256, BK = 64;
constexpr int NBM = Mm / BM;          // 64
constexpr int NBN = Nn / BN;          // 24
constexpr int NWG = NBM * NBN;        // 1536 (divisible by 8 -> bijective XCD swizzle)
constexpr int NITER = (Kk / BK) / 2;  // 16 iterations, 2 K-tiles each

#define GLL16(GSRC, LDST) \
  __builtin_amdgcn_global_load_lds((const __attribute__((address_space(1))) void*)(GSRC), \
                                   (__attribute__((address_space(3))) void*)(LDST), 16, 0, 0)

// stage one half-tile (256 rows x 32 k) : 2 x global_load_lds(16B) per thread
#define STAGE_A(BUF, KH, KOFS) do { \
    bf16_t* _d = sA + ((BUF) * 2 + (KH)) * 8192 + wid * 512; \
    GLL16(srcA0 + (KOFS), _d); \
    GLL16(srcA1 + (KOFS), _d + 4096); \
} while (0)

#define STAGE_B(BUF, KH, KOFS) do { \
    bf16_t* _d = sB + ((BUF) * 2 + (KH)) * 8192 + wid * 512; \
    GLL16(srcB0 + (KOFS), _d); \
    GLL16(srcB1 + (KOFS), _d + 4096); \
} while (0)

#define NO_STAGE ((void)0)
#define W_NOW    ((void)0)
#define W_V4     asm volatile("s_waitcnt vmcnt(4)" ::: "memory")
#define W_V0     asm volatile("s_waitcnt vmcnt(0)" ::: "memory")

// one phase: ds-read frags | stage | barrier | lgkm(0) | 16 MFMA | wait | barrier
#define PHASE(BUF, KS, MH, LOADB, STAGE, WAIT) do { \
    _Pragma("unroll") \
    for (int mf = 0; mf < 4; ++mf) { \
        int r = wm * 128 + (MH) * 64 + mf * 16 + (lane & 15); \
        int q = r * 4 + (kc ^ ((r >> 1) & 3)); \
        a[mf] = *(const bf16x8*)(sA + ((BUF) * 2 + (KS)) * 8192 + q * 8); \
    } \
    if (LOADB) { \
        _Pragma("unroll") \
        for (int nf = 0; nf < 4; ++nf) { \
            int cr = wn * 64 + nf * 16 + (lane & 15); \
            int q = cr * 4 + (kc ^ ((cr >> 1) & 3)); \
            b[nf] = *(const bf16x8*)(sB + ((BUF) * 2 + (KS)) * 8192 + q * 8); \
        } \
    } \
    STAGE; \
    __builtin_amdgcn_sched_barrier(0); \
    __builtin_amdgcn_s_barrier(); \
    asm volatile("s_waitcnt lgkmcnt(0)" ::: "memory"); \
    __builtin_amdgcn_sched_barrier(0); \
    __builtin_amdgcn_s_setprio(1); \
    _Pragma("unroll") \
    for (int mf = 0; mf < 4; ++mf) { \
        _Pragma("unroll") \
        for (int nf = 0; nf < 4; ++nf) \
            acc[(MH) * 4 + mf][nf] = __builtin_amdgcn_mfma_f32_16x16x32_bf16( \
                a[mf], b[nf], acc[(MH) * 4 + mf][nf], 0, 0, 0); \
    } \
    __builtin_amdgcn_s_setprio(0); \
    WAIT; \
    __builtin_amdgcn_sched_barrier(0); \
    __builtin_amdgcn_s_barrier(); \
} while (0)

__global__ __launch_bounds__(512, 2)
void qkv_gemm8(const bf16_t* __restrict__ xb, const bf16_t* __restrict__ wb,
               float* __restrict__ out)
{
    extern __shared__ __attribute__((aligned(16))) char smem_raw[];
    bf16_t* sA = (bf16_t*)smem_raw;                 // [2 buf][2 kh][8192]  64 KiB
    bf16_t* sB = (bf16_t*)(smem_raw + 65536);       // [2 buf][2 kh][8192]  64 KiB

    const int tid  = threadIdx.x;
    const int lane = tid & 63;
    const int wid  = tid >> 6;     // 0..7
    const int wm   = wid >> 2;     // 0..1 (128-row half)
    const int wn   = wid & 3;      // 0..3 (64-col quarter)
    const int kc   = lane >> 4;    // frag k-chunk 0..3

    // XCD-bijective swizzle (NWG % 8 == 0)
    int wg = blockIdx.x;
    wg = (wg & 7) * (NWG >> 3) + (wg >> 3);
    const int bm = wg / NBN, bn = wg % NBN;
    const int m0 = bm * BM, n0 = bn * BN;

    // per-thread staging source pointers (pre-swizzled global source, rule #21)
    const int r0  = tid >> 2;
    const int cl0 = (tid & 3) ^ ((r0 >> 1) & 3);
    const bf16_t* srcA0 = xb + (size_t)(m0 + r0) * Kk + cl0 * 8;
    const bf16_t* srcA1 = srcA0 + (size_t)128 * Kk;
    const bf16_t* srcB0 = wb + (size_t)(n0 + r0) * Kk + cl0 * 8;
    const bf16_t* srcB1 = srcB0 + (size_t)128 * Kk;

    bf16x8 a[4], b[4];
    f32x4 acc[8][4] = {};

    // prologue: tile0 (buf0) fully + tile1 (buf1) kh0; land tile0, keep 2 in flight
    STAGE_A(0, 0, 0);  STAGE_B(0, 0, 0);
    STAGE_A(0, 1, 32); STAGE_B(0, 1, 32);
    STAGE_A(1, 0, 64); STAGE_B(1, 0, 64);
    asm volatile("s_waitcnt vmcnt(4)" ::: "memory");
    __builtin_amdgcn_s_barrier();

#pragma unroll 1
    for (int it = 0; it < NITER - 1; ++it) {
        const int kb = it * 128;
        PHASE(0, 0, 0, 1, STAGE_A(1, 1, kb +  96), W_NOW);
        PHASE(0, 0, 1, 0, STAGE_B(1, 1, kb +  96), W_NOW);
        PHASE(0, 1, 0, 1, STAGE_A(0, 0, kb + 128), W_NOW);
        PHASE(0, 1, 1, 0, STAGE_B(0, 0, kb + 128), W_V4);
        PHASE(1, 0, 0, 1, STAGE_A(0, 1, kb + 160), W_NOW);
        PHASE(1, 0, 1, 0, STAGE_B(0, 1, kb + 160), W_NOW);
        PHASE(1, 1, 0, 1, STAGE_A(1, 0, kb + 192), W_NOW);
        PHASE(1, 1, 1, 0, STAGE_B(1, 0, kb + 192), W_V4);
    }
    // peeled last iteration (tiles 30,31): only buf1.kh1 still needs staging
    PHASE(0, 0, 0, 1, STAGE_A(1, 1, 2016), W_NOW);
    PHASE(0, 0, 1, 0, STAGE_B(1, 1, 2016), W_NOW);
    PHASE(0, 1, 0, 1, NO_STAGE, W_NOW);
    PHASE(0, 1, 1, 0, NO_STAGE, W_V0);
    PHASE(1, 0, 0, 1, NO_STAGE, W_NOW);
    PHASE(1, 0, 1, 0, NO_STAGE, W_NOW);
    PHASE(1, 1, 0, 1, NO_STAGE, W_NOW);
    PHASE(1, 1, 1, 0, NO_STAGE, W_NOW);

    // epilogue: block cols span 2 heads (DK=128); per-wave head is constant.
    // Non-temporal stores (output must not thrash L3), line-contiguous order:
    // for fixed (i, r) the nf-loop writes 4 x 64B consecutive segments.
    const int which = n0 >> 11;
    const int hh    = ((n0 & (Ee - 1)) >> 7) + (wn >> 1);
    const int bb    = m0 >> 12;
    const int s0    = (m0 & (Ss - 1)) + wm * 128;
    float* obase = out + (((size_t)(which * Bb + bb) * Hh + hh) * Ss + s0) * Dk + (wn & 1) * 64;

#pragma unroll
    for (int mh = 0; mh < 2; ++mh)
#pragma unroll
        for (int mf = 0; mf < 4; ++mf)
#pragma unroll
            for (int r = 0; r < 4; ++r)
#pragma unroll
                for (int nf = 0; nf < 4; ++nf) {
                    const int row = mh * 64 + mf * 16 + (lane >> 4) * 4 + r;
                    const int col = nf * 16 + (lane & 15);
                    __builtin_nontemporal_store(acc[mh * 4 + mf][nf][r],
                                                &obase[(size_t)row * Dk + col]);
                }
}

// ------------------------------------------- fallback (round-1, fp32 staging)
constexpr int FTM = 128, FTN = 128, FTK = 64;
constexpr int FNKT = Kk / FTK;

__global__ __launch_bounds__(256, 2)
void qkv_gemm_fb(const float* __restrict__ x, const float* __restrict__ w,
                 float* __restrict__ out)
{
    __shared__ __attribute__((aligned(16))) bf16_t lA[2][FTM * FTK];
    __shared__ __attribute__((aligned(16))) bf16_t lB[2][FTN * FTK];

    const int tid = threadIdx.x, lane = tid & 63, wid = tid >> 6;
    const int wm = wid >> 1, wn = wid & 1;
    const int n0 = blockIdx.x * FTN, m0 = blockIdx.y * FTM;
    f32x4 ra[8], rb[8];

    auto load_regs = [&](int kt) {
        const int k0 = kt * FTK;
#pragma unroll
        for (int i = 0; i < 4; ++i) {
            const int c = tid + i * 256, row = c >> 3, cir = c & 7;
            const float* pa = x + (size_t)(m0 + row) * Kk + k0 + cir * 8;
            const float* pb = w + (size_t)(n0 + row) * Kk + k0 + cir * 8;
            ra[i*2+0] = *(const f32x4*)(pa); ra[i*2+1] = *(const f32x4*)(pa+4);
            rb[i*2+0] = *(const f32x4*)(pb); rb[i*2+1] = *(const f32x4*)(pb+4);
        }
    };
    auto store_lds = [&](int buf) {
#pragma unroll
        for (int i = 0; i < 4; ++i) {
            const int c = tid + i * 256, row = c >> 3, cir = c & 7;
            const int chunk = row * 8 + (cir ^ (row & 7));
            bf16x8 va, vb;
#pragma unroll
            for (int j = 0; j < 4; ++j) {
                va[j] = (bf16_t)ra[i*2+0][j]; va[j+4] = (bf16_t)ra[i*2+1][j];
                vb[j] = (bf16_t)rb[i*2+0][j]; vb[j+4] = (bf16_t)rb[i*2+1][j];
            }
            *(bf16x8*)(&lA[buf][chunk*8]) = va;
            *(bf16x8*)(&lB[buf][chunk*8]) = vb;
        }
    };
    f32x4 acc[4][4] = {};
    auto compute = [&](int buf) {
#pragma unroll
        for (int ks = 0; ks < 2; ++ks) {
            bf16x8 af[4], bfr[4];
#pragma unroll
            for (int mi = 0; mi < 4; ++mi) {
                const int row = wm*64 + mi*16 + (lane & 15);
                const int cir = ks*4 + (lane >> 4);
                af[mi] = *(const bf16x8*)(&lA[buf][(row*8 + (cir ^ (row & 7)))*8]);
            }
#pragma unroll
            for (int ni = 0; ni < 4; ++ni) {
                const int row = wn*64 + ni*16 + (lane & 15);
                const int cir = ks*4 + (lane >> 4);
                bfr[ni] = *(const bf16x8*)(&lB[buf][(row*8 + (cir ^ (row & 7)))*8]);
            }
#pragma unroll
            for (int mi = 0; mi < 4; ++mi)
#pragma unroll
                for (int ni = 0; ni < 4; ++ni)
                    acc[mi][ni] = __builtin_amdgcn_mfma_f32_16x16x32_bf16(af[mi], bfr[ni], acc[mi][ni], 0, 0, 0);
        }
    };

    load_regs(0); store_lds(0);
    int cur = 0;
#pragma unroll 1
    for (int kt = 0; kt < FNKT; ++kt) {
        __syncthreads();
        if (kt + 1 < FNKT) load_regs(kt + 1);
        compute(cur);
        if (kt + 1 < FNKT) store_lds(cur ^ 1);
        cur ^= 1;
    }
    const int b = m0 / Ss, s0g = m0 % Ss;
    const int which = n0 >> 11, h = (n0 & (Ee - 1)) >> 7;
    float* obase = out + ((size_t)((which * Bb + b) * Hh + h) * Ss + s0g) * Dk;
#pragma unroll
    for (int mi = 0; mi < 4; ++mi)
#pragma unroll
        for (int ni = 0; ni < 4; ++ni)
#pragma unroll
            for (int r = 0; r < 4; ++r) {
                const int rowL = wm*64 + mi*16 + (lane >> 4)*4 + r;
                const int colL = wn*64 + ni*16 + (lane & 15);
                obase[(size_t)rowL * Dk + colL] = acc[mi][ni][r];
            }
}

// ---------------------------------------------------------------- launcher
extern "C" void kernel_launch(void* const* d_in, const int* in_sizes, int n_in,
                              void* d_out, int out_size, void* d_ws, size_t ws_size,
                              hipStream_t stream) {
    const float* x = (const float*)d_in[0];     // [B,S,E] fp32
    const float* w = (const float*)d_in[1];     // [3E, E] fp32
    float* out = (float*)d_out;

    const size_t xb_bytes = (size_t)Mm * Kk * 2;
    const size_t wb_bytes = (size_t)Nn * Kk * 2;

    if (ws_size >= xb_bytes + wb_bytes) {
        bf16_t* xb = (bf16_t*)d_ws;
        bf16_t* wb = (bf16_t*)((char*)d_ws + xb_bytes);
        cast_f32_to_bf16<<<2048, 256, 0, stream>>>(x, w, xb, wb);
        hipFuncSetAttribute((const void*)qkv_gemm8,
                            hipFuncAttributeMaxDynamicSharedMemorySize, 131072);
        qkv_gemm8<<<NWG, 512, 131072, stream>>>(xb, wb, out);
    } else {
        dim3 grid(Nn / FTN, Mm / FTM);
        qkv_gemm_fb<<<grid, dim3(256), 0, stream>>>(x, w, out);
    }
}